// Round 1
// baseline (323.202 us; speedup 1.0000x reference)
//
#include <hip/hip_runtime.h>

// out[token][0:64] = relu(W[x[token]][0:64] + b[0:64]) + 1e-5
// x: int32 [2048*2048], W: f32 [100000][64], b: f32 [64], out: f32 [2048*2048][64]
// 16 threads per token, one float4 (4 floats) per thread.

__global__ __launch_bounds__(256) void gather_bias_relu_kernel(
    const int* __restrict__ x,
    const float4* __restrict__ W4,   // [100000][16] float4
    const float4* __restrict__ b4,   // [16] float4
    float4* __restrict__ out4,       // [ntok][16] float4
    int ntok)
{
    const int j = threadIdx.x & 15;          // float4 slot within the 64-dim row
    const float4 bias = b4[j];

    int tid = blockIdx.x * blockDim.x + threadIdx.x;
    int token = tid >> 4;
    const int token_stride = (gridDim.x * blockDim.x) >> 4;

    for (; token < ntok; token += token_stride) {
        const int idx = x[token];            // broadcast across the 16-thread group
        float4 w = W4[(size_t)idx * 16 + j];
        float4 r;
        r.x = fmaxf(w.x + bias.x, 0.0f) + 1e-5f;
        r.y = fmaxf(w.y + bias.y, 0.0f) + 1e-5f;
        r.z = fmaxf(w.z + bias.z, 0.0f) + 1e-5f;
        r.w = fmaxf(w.w + bias.w, 0.0f) + 1e-5f;
        out4[(size_t)token * 16 + j] = r;
    }
}

extern "C" void kernel_launch(void* const* d_in, const int* in_sizes, int n_in,
                              void* d_out, int out_size, void* d_ws, size_t ws_size,
                              hipStream_t stream) {
    const int*    x  = (const int*)d_in[0];
    const float*  W  = (const float*)d_in[1];
    const float*  b  = (const float*)d_in[2];
    float*        out = (float*)d_out;

    const int ntok = in_sizes[0];            // 2048*2048

    const int block = 256;
    const int grid  = 2048;                  // grid-stride; 256 CUs * 8 blocks

    gather_bias_relu_kernel<<<grid, block, 0, stream>>>(
        x,
        (const float4*)W,
        (const float4*)b,
        (float4*)out,
        ntok);
}

// Round 3
// 300.800 us; speedup vs baseline: 1.0745x; 1.0745x over previous
//
#include <hip/hip_runtime.h>

// out[token][0:64] = relu(W[x[token]][0:64] + b[0:64]) + 1e-5
// x: int32 [2048*2048], W: f32 [100000][64], b: f32 [64], out: f32 [2048*2048][64]
// 16 threads per token, one 16B vector per thread; 4-token unroll for gather MLP;
// nontemporal stores so the 1 GB output stream doesn't evict W from L2/L3.

typedef float f32x4 __attribute__((ext_vector_type(4)));

__global__ __launch_bounds__(256) void gather_bias_relu_kernel(
    const int* __restrict__ x,
    const f32x4* __restrict__ W4,    // [100000][16] f32x4
    const f32x4* __restrict__ b4,    // [16] f32x4
    f32x4* __restrict__ out4,        // [ntok][16] f32x4
    int ntok)
{
    const int j = threadIdx.x & 15;          // 16B slot within the 64-float row
    const f32x4 bias = b4[j];

    const int group   = (blockIdx.x * blockDim.x + threadIdx.x) >> 4;
    const int ngroups = (gridDim.x * blockDim.x) >> 4;   // token-groups in flight

    int t = group;
    // Unrolled main loop: 4 tokens in flight per thread -> 4 independent
    // dependent-chains (x-load -> W-gather) overlap.
    for (; t + 3 * ngroups < ntok; t += 4 * ngroups) {
        const int t0 = t;
        const int t1 = t + ngroups;
        const int t2 = t + 2 * ngroups;
        const int t3 = t + 3 * ngroups;

        const int i0 = x[t0];
        const int i1 = x[t1];
        const int i2 = x[t2];
        const int i3 = x[t3];

        f32x4 w0 = W4[(size_t)i0 * 16 + j];
        f32x4 w1 = W4[(size_t)i1 * 16 + j];
        f32x4 w2 = W4[(size_t)i2 * 16 + j];
        f32x4 w3 = W4[(size_t)i3 * 16 + j];

        f32x4 r0, r1, r2, r3;
        #pragma unroll
        for (int c = 0; c < 4; ++c) {
            r0[c] = fmaxf(w0[c] + bias[c], 0.0f) + 1e-5f;
            r1[c] = fmaxf(w1[c] + bias[c], 0.0f) + 1e-5f;
            r2[c] = fmaxf(w2[c] + bias[c], 0.0f) + 1e-5f;
            r3[c] = fmaxf(w3[c] + bias[c], 0.0f) + 1e-5f;
        }

        __builtin_nontemporal_store(r0, &out4[(size_t)t0 * 16 + j]);
        __builtin_nontemporal_store(r1, &out4[(size_t)t1 * 16 + j]);
        __builtin_nontemporal_store(r2, &out4[(size_t)t2 * 16 + j]);
        __builtin_nontemporal_store(r3, &out4[(size_t)t3 * 16 + j]);
    }
    // Tail
    for (; t < ntok; t += ngroups) {
        const int idx = x[t];
        f32x4 w = W4[(size_t)idx * 16 + j];
        f32x4 r;
        #pragma unroll
        for (int c = 0; c < 4; ++c)
            r[c] = fmaxf(w[c] + bias[c], 0.0f) + 1e-5f;
        __builtin_nontemporal_store(r, &out4[(size_t)t * 16 + j]);
    }
}

extern "C" void kernel_launch(void* const* d_in, const int* in_sizes, int n_in,
                              void* d_out, int out_size, void* d_ws, size_t ws_size,
                              hipStream_t stream) {
    const int*   x   = (const int*)d_in[0];
    const float* W   = (const float*)d_in[1];
    const float* b   = (const float*)d_in[2];
    float*       out = (float*)d_out;

    const int ntok = in_sizes[0];            // 2048*2048

    const int block = 256;
    const int grid  = 2048;                  // 32768 token-groups, 128 tokens each

    gather_bias_relu_kernel<<<grid, block, 0, stream>>>(
        x,
        (const f32x4*)W,
        (const f32x4*)b,
        (f32x4*)out,
        ntok);
}

// Round 4
// 291.304 us; speedup vs baseline: 1.1095x; 1.0326x over previous
//
#include <hip/hip_runtime.h>

// out[token][0:64] = relu(W[x[token]][0:64] + b[0:64]) + 1e-5
// x: int32 [4194304], W: f32 [100000][64], b: f32 [64], out: f32 [4194304][64]
//
// Multi-pass category-range gather: pass p handles tokens with idx in
// [p*8192, (p+1)*8192) so the active 2 MB W-chunk stays resident in each
// XCD's 4 MB L2 instead of being thrashed by the 1 GB output stream.
// Each block pins its 2048-token index slab in LDS (8 KB) so x is read
// from HBM exactly once.

typedef float f32x4 __attribute__((ext_vector_type(4)));

#define TOKENS_PER_BLOCK 2048
#define CAT_SHIFT 13                                   // 8192 cats = 2 MB chunk
#define NUM_CATS 100000
#define NPASS ((NUM_CATS + (1 << CAT_SHIFT) - 1) >> CAT_SHIFT)   // 13

__global__ __launch_bounds__(256) void gather_bias_relu_kernel(
    const int* __restrict__ x,
    const f32x4* __restrict__ W4,    // [100000][16] f32x4
    const f32x4* __restrict__ b4,    // [16] f32x4
    f32x4* __restrict__ out4,        // [ntok][16] f32x4
    int ntok)
{
    __shared__ int s_idx[TOKENS_PER_BLOCK];

    const int tid  = threadIdx.x;
    const int base = blockIdx.x * TOKENS_PER_BLOCK;
    const int nblk = min(TOKENS_PER_BLOCK, ntok - base);

    // Stage this block's x-slab into LDS, coalesced 16B loads.
    if (base + TOKENS_PER_BLOCK <= ntok) {
        const int4* xs = (const int4*)(x + base);
        #pragma unroll
        for (int i = 0; i < TOKENS_PER_BLOCK / 4 / 256; ++i)
            ((int4*)s_idx)[tid + i * 256] = xs[tid + i * 256];
    } else {
        for (int i = tid; i < nblk; i += 256) s_idx[i] = x[base + i];
    }
    __syncthreads();

    const int j = tid & 15;                 // 16B slot within the 64-float row
    const f32x4 bias = b4[j];
    const int group = tid >> 4;             // 0..15 token-groups per block

    for (int pass = 0; pass < NPASS; ++pass) {
        for (int t = group; t < nblk; t += 16) {
            const int idx = s_idx[t];       // LDS broadcast to the 16 lanes
            if ((idx >> CAT_SHIFT) == pass) {
                f32x4 w = W4[(size_t)idx * 16 + j];
                f32x4 r;
                #pragma unroll
                for (int c = 0; c < 4; ++c)
                    r[c] = fmaxf(w[c] + bias[c], 0.0f) + 1e-5f;
                __builtin_nontemporal_store(r, &out4[(size_t)(base + t) * 16 + j]);
            }
        }
    }
}

extern "C" void kernel_launch(void* const* d_in, const int* in_sizes, int n_in,
                              void* d_out, int out_size, void* d_ws, size_t ws_size,
                              hipStream_t stream) {
    const int*   x   = (const int*)d_in[0];
    const float* W   = (const float*)d_in[1];
    const float* b   = (const float*)d_in[2];
    float*       out = (float*)d_out;

    const int ntok = in_sizes[0];            // 4,194,304
    const int grid = (ntok + TOKENS_PER_BLOCK - 1) / TOKENS_PER_BLOCK;  // 2048

    gather_bias_relu_kernel<<<grid, 256, 0, stream>>>(
        x,
        (const f32x4*)W,
        (const f32x4*)b,
        (f32x4*)out,
        ntok);
}